// Round 2
// baseline (206.392 us; speedup 1.0000x reference)
//
#include <hip/hip_runtime.h>

// Problem: B=8, L=2048, H=256. fp32 in/out.
#define B_ 8
#define L_ 2048
#define H_ 256

typedef _Float16 half8 __attribute__((ext_vector_type(8)));
typedef _Float16 half4_t __attribute__((ext_vector_type(4)));
typedef float f32x4 __attribute__((ext_vector_type(4)));

__device__ __forceinline__ float fast_tanh(float x) {
    const float e2 = __expf(2.f * x);
    return 1.f - 2.f * __builtin_amdgcn_rcpf(e2 + 1.f);
}

// ---------------------------------------------------------------------------
// prep: one block = 64 rows of text (mat=0) or opin (mat=1).
// MFMA GEMM rows@W^T (fp16 in, fp32 acc), epilogue tanh/wa reduce.
// mat=0 -> ws_st[row]; mat=1 -> ws_cm[row]={c*mult,mult} and V^T fp16 -> vtg.
// (unchanged from verified baseline)
// ---------------------------------------------------------------------------
__global__ __launch_bounds__(256, 2) void prep_kernel(
    const float* __restrict__ opin, const float* __restrict__ text,
    const int* __restrict__ pos_ids,
    const float* __restrict__ Wt, const float* __restrict__ bt,
    const float* __restrict__ Wo, const float* __restrict__ wa,
    const float* __restrict__ ba,
    float* __restrict__ ws_st, float2* __restrict__ ws_cm,
    _Float16* __restrict__ vtg)
{
    __shared__ __align__(16) _Float16 a_lds[4][8][512];  // [rowgrp][kchunk][frag-linear]
    __shared__ __align__(16) _Float16 w_lds[16][512];    // [ntile][frag-linear], per chunk

    const int tid  = threadIdx.x;
    const int lane = tid & 63;
    const int rg   = tid >> 6;                 // wave id = 16-row group
    const int mat  = blockIdx.x & 1;           // 0=text, 1=opin
    const size_t g0 = (size_t)(blockIdx.x >> 1) * 64;   // first flattened row (b*L+i)

    const float* __restrict__ src = mat ? opin : text;
    const float* __restrict__ W   = mat ? Wo   : Wt;

    // ---- stage A: 64 rows x 256 k, fp32 -> fp16, frag-linear per (rg, kc) ----
    for (int v = 0; v < 16; ++v) {
        const int idx = v * 256 + tid;      // float4 index in 64x64 grid
        const int row = idx >> 6;           // 0..63
        const int k   = (idx & 63) * 4;     // 0..252
        const float4 f = *(const float4*)(src + (g0 + row) * 256 + k);
        half4_t h = { (_Float16)f.x, (_Float16)f.y, (_Float16)f.z, (_Float16)f.w };
        const int off = ((row & 15) + 16 * ((k >> 3) & 3)) * 8 + (k & 7); // k&7 in {0,4}
        *(half4_t*)&a_lds[row >> 4][k >> 5][off] = h;
    }
    __syncthreads();

    f32x4 acc[16];
#pragma unroll
    for (int nt = 0; nt < 16; ++nt) acc[nt] = (f32x4){0.f, 0.f, 0.f, 0.f};

    for (int kc = 0; kc < 8; ++kc) {
        // stage W chunk: 256 n x 32 k
        for (int p = 0; p < 8; ++p) {
            const int n = p * 32 + (tid >> 3);
            const int k = (tid & 7) * 4;    // within chunk
            const float4 f = *(const float4*)(W + n * 256 + kc * 32 + k);
            half4_t h = { (_Float16)f.x, (_Float16)f.y, (_Float16)f.z, (_Float16)f.w };
            const int off = ((n & 15) + 16 * (k >> 3)) * 8 + (k & 7);
            *(half4_t*)&w_lds[n >> 4][off] = h;
        }
        __syncthreads();
        const half8 afrag = *(const half8*)&a_lds[rg][kc][lane * 8];
#pragma unroll
        for (int nt = 0; nt < 16; ++nt) {
            const half8 bfrag = *(const half8*)&w_lds[nt][lane * 8];
            acc[nt] = __builtin_amdgcn_mfma_f32_16x16x32_f16(afrag, bfrag, acc[nt], 0, 0, 0);
        }
        __syncthreads();
    }

    // ---- epilogue: rowsum_n( tanh(acc + bt?) * wa ) ----
    const int em = lane & 15, q = lane >> 4;
    float rowsum[4] = {0.f, 0.f, 0.f, 0.f};
#pragma unroll
    for (int nt = 0; nt < 16; ++nt) {
        const int col  = nt * 16 + em;
        const float btv = mat ? 0.f : bt[col];
        const float wav = wa[mat * 256 + col];
#pragma unroll
        for (int r = 0; r < 4; ++r)
            rowsum[r] += fast_tanh(acc[nt][r] + btv) * wav;
    }
#pragma unroll
    for (int r = 0; r < 4; ++r) {
        float s = rowsum[r];
        s += __shfl_xor(s, 1, 64);
        s += __shfl_xor(s, 2, 64);
        s += __shfl_xor(s, 4, 64);
        s += __shfl_xor(s, 8, 64);
        if (em == 0) {
            const size_t grow = g0 + rg * 16 + q * 4 + r;
            if (mat == 0) {
                ws_st[grow] = s;
            } else {
                const int p = pos_ids[grow];
                const bool isop = (p==19)|(p==20)|(p==21)|(p==33)|(p==34)|(p==35)|((p>=41)&(p<=46));
                const float mult = isop ? 8.f : 1.f;
                const float c = s + ba[0];
                ws_cm[grow] = make_float2(c * mult, mult);
            }
        }
    }

    // ---- V^T emission (opin blocks): vtg[(b*256+h)*2048 + j] fp16 ----
    if (mat == 1) {
        const int h = tid;
        const size_t b = g0 >> 11;
        const int j0 = (int)(g0 & 2047);
        const int kc = h >> 5, kq = (h >> 3) & 3, jh = h & 7;
        _Float16 vals[64];
#pragma unroll
        for (int r = 0; r < 64; ++r)
            vals[r] = a_lds[r >> 4][kc][((r & 15) + 16 * kq) * 8 + jh];
        _Float16* dst = vtg + ((b * 256 + h) * 2048 + j0);
#pragma unroll
        for (int w = 0; w < 8; ++w)
            *(half8*)(dst + w * 8) = *(half8*)&vals[w * 8];
    }
}

// ---------------------------------------------------------------------------
// attn v3: one block = (batch b, 64-row i-tile), FULL 256 h.  512 thr, 8 waves.
//  - scores computed ONCE per (i,j); row-local softmax (8 lanes/row, 3 shfls)
//  - bias via LDS table base[d]*log2e; exp via raw v_exp_f32
//  - V^T B-fragments: PINNED inline-asm global_load_dwordx4 into a single
//    32-VGPR buffer, issued for chunk k+1 right after chunk k's MFMAs,
//    drained by explicit s_waitcnt vmcnt(0) + sched_barrier before use
//    (v2's plain-C++ prefetch was sunk to use point by the compiler ->
//     VGPR_Count=76 proved the buffers were never register-resident)
//  - p_lds store XOR-swizzle: slot = ((row&15) ^ (kq<<1)) + 16*kq
//    (v2's layout was an 8-way write conflict: 256B kq-stride = same bank)
//  - ONE __syncthreads per chunk (P and alpha double-buffered in LDS)
// ---------------------------------------------------------------------------
__global__ __launch_bounds__(512, 2) void attn_kernel(
    const float* __restrict__ ws_st, const float2* __restrict__ ws_cm,
    const _Float16* __restrict__ vtg, float* __restrict__ out)
{
    __shared__ float t_lds[2048];                           // base[d]*log2e, 8 KB
    __shared__ __align__(16) _Float16 p_lds[2][4][2][512];  // [buf][rt][ks][frag-linear]
    __shared__ float alpha_lds[2][64];
    __shared__ float z_lds[64];

    const int tid  = threadIdx.x;
    const int lane = tid & 63;
    const int wid  = tid >> 6;                // 0..7
    const int rgp  = wid & 1;                 // MFMA rows rgp*32 .. +31
    const int hq   = wid >> 1;                // MFMA cols hq*64 .. +63
    const int em   = lane & 15;
    const int q4   = lane >> 4;

    const int b  = blockIdx.x & 7;            // consecutive blocks spread batches
    const int i0 = (blockIdx.x >> 3) * 64;

    const int row = tid >> 3;                 // scoring row 0..63 (8 lanes/row)
    const int jg  = tid & 7;                  // 8-j group within chunk
    const int gi  = i0 + row;

    // ---- bias table: d==0 ? 0.5 : 1/log2(2+d), scaled by log2(e) ----
#pragma unroll
    for (int v = 0; v < 4; ++v) {
        const int d = tid * 4 + v;
        const float bv = (d == 0) ? 0.5f : 1.0f / __log2f(2.f + (float)d);
        t_lds[d] = bv * 1.44269504088896f;
    }

    const float sti = ws_st[b * 2048 + gi];
    // per-lane V^T base: hcol = hq*64 + ht*16 + em, k-slice q4 -> j = ks*32+q4*8+v
    const _Float16* __restrict__ vb =
        vtg + ((size_t)(b * 256 + hq * 64 + em)) * 2048 + q4 * 8;

    f32x4 acc[2][4];
#pragma unroll
    for (int rt = 0; rt < 2; ++rt)
#pragma unroll
        for (int ht = 0; ht < 4; ++ht) acc[rt][ht] = (f32x4){0.f, 0.f, 0.f, 0.f};
    float m_run = -1e30f;
    float zacc  = 0.f;

    // pinned V^T fragment buffer: 8 x 16B = 32 VGPRs, asm-written so the
    // compiler can neither sink nor rematerialize the loads
    f32x4 vbuf[2][4];
    // prologue: issue chunk-0 fragments
#pragma unroll
    for (int ks = 0; ks < 2; ++ks)
#pragma unroll
        for (int ht = 0; ht < 4; ++ht)
            asm volatile("global_load_dwordx4 %0, %1, off"
                         : "=v"(vbuf[ks][ht])
                         : "v"(vb + ht * 32768 + ks * 32));

    __syncthreads();   // t_lds ready

    for (int kc = 0; kc < 32; ++kc) {
        const int j0  = kc * 64;
        const int buf = kc & 1;

        // --- scores: 8 j per lane, bias from table ---
        float s_arr[8];
        float mx = -1e30f;
        {
            const float4* __restrict__ cmp =
                (const float4*)(ws_cm + b * 2048 + j0 + jg * 8);
#pragma unroll
            for (int w = 0; w < 4; ++w) {
                const float4 c4 = cmp[w];          // {c0*m0, m0, c1*m1, m1}
                const int jj = j0 + jg * 8 + w * 2;
                int d0 = gi - jj;     d0 = d0 < 0 ? -d0 : d0;
                int d1 = gi - jj - 1; d1 = d1 < 0 ? -d1 : d1;
                const float s0 = (sti * c4.y + c4.x) * t_lds[d0];
                const float s1 = (sti * c4.w + c4.z) * t_lds[d1];
                s_arr[2 * w]     = s0;
                s_arr[2 * w + 1] = s1;
                mx = fmaxf(mx, fmaxf(s0, s1));
            }
        }
        // row max across the row's 8 lanes (consecutive, 8-aligned)
        mx = fmaxf(mx, __shfl_xor(mx, 1, 64));
        mx = fmaxf(mx, __shfl_xor(mx, 2, 64));
        mx = fmaxf(mx, __shfl_xor(mx, 4, 64));

        const float m_new = fmaxf(m_run, mx);
        const float alpha = __builtin_amdgcn_exp2f(m_run - m_new); // ==1 if no update
        float zl = 0.f;
        half8 pv;
#pragma unroll
        for (int v = 0; v < 8; ++v) {
            const float p = __builtin_amdgcn_exp2f(s_arr[v] - m_new);
            zl += p;
            pv[v] = (_Float16)p;
        }
        zacc  = zacc * alpha + zl;
        m_run = m_new;

        // P frag-linear with XOR swizzle: slot = ((r&15)^(kq<<1)) + 16*kq
        {
            const int kq = jg & 3;
            const int slot = (((row & 15) ^ (kq << 1)) + 16 * kq);
            *(half8*)&p_lds[buf][row >> 4][jg >> 2][slot * 8] = pv;
        }
        if (jg == 0) alpha_lds[buf][row] = alpha;

        __syncthreads();   // the ONLY barrier per chunk

        // --- rescale acc by per-row alpha (broadcast reads, conflict-free) ---
        {
            float ar[2][4];
            bool upd = false;
#pragma unroll
            for (int rt = 0; rt < 2; ++rt)
#pragma unroll
                for (int r = 0; r < 4; ++r) {
                    ar[rt][r] = alpha_lds[buf][rgp * 32 + rt * 16 + q4 * 4 + r];
                    upd |= (ar[rt][r] != 1.f);
                }
            if (__any(upd)) {
#pragma unroll
                for (int rt = 0; rt < 2; ++rt)
#pragma unroll
                    for (int ht = 0; ht < 4; ++ht)
#pragma unroll
                        for (int r = 0; r < 4; ++r)
                            acc[rt][ht][r] *= ar[rt][r];
            }
        }

        // --- drain the pinned loads; fence so MFMAs can't hoist above ---
        asm volatile("s_waitcnt vmcnt(0)" ::: "memory");
        __builtin_amdgcn_sched_barrier(0);

        // --- MFMA: P(64x64) @ V^T-cols, B-fragments in pinned regs ---
        {
            const int sl = (lane ^ (q4 << 1)) * 8;   // read-side swizzle
#pragma unroll
            for (int ks = 0; ks < 2; ++ks) {
                const half8 a0 = *(const half8*)&p_lds[buf][rgp * 2 + 0][ks][sl];
                const half8 a1 = *(const half8*)&p_lds[buf][rgp * 2 + 1][ks][sl];
#pragma unroll
                for (int ht = 0; ht < 4; ++ht) {
                    const half8 bh = __builtin_bit_cast(half8, vbuf[ks][ht]);
                    acc[0][ht] = __builtin_amdgcn_mfma_f32_16x16x32_f16(a0, bh, acc[0][ht], 0, 0, 0);
                    acc[1][ht] = __builtin_amdgcn_mfma_f32_16x16x32_f16(a1, bh, acc[1][ht], 0, 0, 0);
                }
            }
        }

        // --- issue next chunk's fragments (regs free after MFMA consumption) ---
        if (kc < 31) {
#pragma unroll
            for (int ks = 0; ks < 2; ++ks)
#pragma unroll
                for (int ht = 0; ht < 4; ++ht)
                    asm volatile("global_load_dwordx4 %0, %1, off"
                                 : "=v"(vbuf[ks][ht])
                                 : "v"(vb + ht * 32768 + (j0 + 64) + ks * 32));
        }
    }

    // --- Z finalize: reduce the row's 8 lanes, publish ---
    zacc += __shfl_xor(zacc, 1, 64);
    zacc += __shfl_xor(zacc, 2, 64);
    zacc += __shfl_xor(zacc, 4, 64);
    if (jg == 0) z_lds[row] = zacc;
    __syncthreads();

    // --- epilogue: normalize, store. C/D: col=lane&15, row=(lane>>4)*4+reg ---
#pragma unroll
    for (int rt = 0; rt < 2; ++rt) {
#pragma unroll
        for (int r = 0; r < 4; ++r) {
            const int orow = rgp * 32 + rt * 16 + q4 * 4 + r;
            const float rz = 1.f / z_lds[orow];
#pragma unroll
            for (int ht = 0; ht < 4; ++ht)
                out[((size_t)b * 2048 + i0 + orow) * 256 + hq * 64 + ht * 16 + em] =
                    acc[rt][ht][r] * rz;
        }
    }
}

// ---------------------------------------------------------------------------
extern "C" void kernel_launch(void* const* d_in, const int* in_sizes, int n_in,
                              void* d_out, int out_size, void* d_ws, size_t ws_size,
                              hipStream_t stream) {
    const float* opin  = (const float*)d_in[0];
    const float* text  = (const float*)d_in[1];
    const int* pos_ids = (const int*)d_in[2];
    const float* Wt    = (const float*)d_in[3];
    const float* bt    = (const float*)d_in[4];
    const float* Wo    = (const float*)d_in[5];
    const float* wa    = (const float*)d_in[6];
    const float* ba    = (const float*)d_in[7];
    float* out         = (float*)d_out;

    // workspace: st (64 KB) | cm (128 KB) | vtg fp16 (8 MB)
    float*  ws_st = (float*)d_ws;
    float2* ws_cm = (float2*)((char*)d_ws + 65536);
    _Float16* vtg = (_Float16*)((char*)d_ws + 65536 + 131072);

    prep_kernel<<<512, 256, 0, stream>>>(opin, text, pos_ids, Wt, bt, Wo, wa, ba,
                                         ws_st, ws_cm, vtg);
    attn_kernel<<<256, 512, 0, stream>>>(ws_st, ws_cm, vtg, out);
}

// Round 3
// 150.664 us; speedup vs baseline: 1.3699x; 1.3699x over previous
//
#include <hip/hip_runtime.h>

// Problem: B=8, L=2048, H=256. fp32 in/out.
#define B_ 8
#define L_ 2048
#define H_ 256

typedef _Float16 half8 __attribute__((ext_vector_type(8)));
typedef _Float16 half4_t __attribute__((ext_vector_type(4)));
typedef float f32x4 __attribute__((ext_vector_type(4)));

__device__ __forceinline__ float fast_tanh(float x) {
    const float e2 = __expf(2.f * x);
    return 1.f - 2.f * __builtin_amdgcn_rcpf(e2 + 1.f);
}

// ---------------------------------------------------------------------------
// prep: one block = 64 rows of text (mat=0) or opin (mat=1).
// MFMA GEMM rows@W^T (fp16 in, fp32 acc), epilogue tanh/wa reduce.
// mat=0 -> ws_st[row]; mat=1 -> ws_cm[row]={c*mult,mult} and V^T -> vtg.
// v4: vtg is emitted in MFMA-fragment-tiled layout
//     vtg[b][kc(32)][ks(2)][q4(4)][h(256)][j8(8)]  (16B unit = one B-frag)
//     -> prep stores become 1KB-contiguous wave-stores (were 4KB-strided 16B)
//     -> attn fragment loads become 8-line wave-loads (were 64-line!)
// ---------------------------------------------------------------------------
__global__ __launch_bounds__(256, 2) void prep_kernel(
    const float* __restrict__ opin, const float* __restrict__ text,
    const int* __restrict__ pos_ids,
    const float* __restrict__ Wt, const float* __restrict__ bt,
    const float* __restrict__ Wo, const float* __restrict__ wa,
    const float* __restrict__ ba,
    float* __restrict__ ws_st, float2* __restrict__ ws_cm,
    _Float16* __restrict__ vtg)
{
    __shared__ __align__(16) _Float16 a_lds[4][8][512];  // [rowgrp][kchunk][frag-linear]
    __shared__ __align__(16) _Float16 w_lds[16][512];    // [ntile][frag-linear], per chunk

    const int tid  = threadIdx.x;
    const int lane = tid & 63;
    const int rg   = tid >> 6;                 // wave id = 16-row group
    const int mat  = blockIdx.x & 1;           // 0=text, 1=opin
    const size_t g0 = (size_t)(blockIdx.x >> 1) * 64;   // first flattened row (b*L+i)

    const float* __restrict__ src = mat ? opin : text;
    const float* __restrict__ W   = mat ? Wo   : Wt;

    // ---- stage A: 64 rows x 256 k, fp32 -> fp16, frag-linear per (rg, kc) ----
    for (int v = 0; v < 16; ++v) {
        const int idx = v * 256 + tid;      // float4 index in 64x64 grid
        const int row = idx >> 6;           // 0..63
        const int k   = (idx & 63) * 4;     // 0..252
        const float4 f = *(const float4*)(src + (g0 + row) * 256 + k);
        half4_t h = { (_Float16)f.x, (_Float16)f.y, (_Float16)f.z, (_Float16)f.w };
        const int off = ((row & 15) + 16 * ((k >> 3) & 3)) * 8 + (k & 7); // k&7 in {0,4}
        *(half4_t*)&a_lds[row >> 4][k >> 5][off] = h;
    }
    __syncthreads();

    f32x4 acc[16];
#pragma unroll
    for (int nt = 0; nt < 16; ++nt) acc[nt] = (f32x4){0.f, 0.f, 0.f, 0.f};

    for (int kc = 0; kc < 8; ++kc) {
        // stage W chunk: 256 n x 32 k
        for (int p = 0; p < 8; ++p) {
            const int n = p * 32 + (tid >> 3);
            const int k = (tid & 7) * 4;    // within chunk
            const float4 f = *(const float4*)(W + n * 256 + kc * 32 + k);
            half4_t h = { (_Float16)f.x, (_Float16)f.y, (_Float16)f.z, (_Float16)f.w };
            const int off = ((n & 15) + 16 * (k >> 3)) * 8 + (k & 7);
            *(half4_t*)&w_lds[n >> 4][off] = h;
        }
        __syncthreads();
        const half8 afrag = *(const half8*)&a_lds[rg][kc][lane * 8];
#pragma unroll
        for (int nt = 0; nt < 16; ++nt) {
            const half8 bfrag = *(const half8*)&w_lds[nt][lane * 8];
            acc[nt] = __builtin_amdgcn_mfma_f32_16x16x32_f16(afrag, bfrag, acc[nt], 0, 0, 0);
        }
        __syncthreads();
    }

    // ---- epilogue: rowsum_n( tanh(acc + bt?) * wa ) ----
    const int em = lane & 15, q = lane >> 4;
    float rowsum[4] = {0.f, 0.f, 0.f, 0.f};
#pragma unroll
    for (int nt = 0; nt < 16; ++nt) {
        const int col  = nt * 16 + em;
        const float btv = mat ? 0.f : bt[col];
        const float wav = wa[mat * 256 + col];
#pragma unroll
        for (int r = 0; r < 4; ++r)
            rowsum[r] += fast_tanh(acc[nt][r] + btv) * wav;
    }
#pragma unroll
    for (int r = 0; r < 4; ++r) {
        float s = rowsum[r];
        s += __shfl_xor(s, 1, 64);
        s += __shfl_xor(s, 2, 64);
        s += __shfl_xor(s, 4, 64);
        s += __shfl_xor(s, 8, 64);
        if (em == 0) {
            const size_t grow = g0 + rg * 16 + q * 4 + r;
            if (mat == 0) {
                ws_st[grow] = s;
            } else {
                const int p = pos_ids[grow];
                const bool isop = (p==19)|(p==20)|(p==21)|(p==33)|(p==34)|(p==35)|((p>=41)&(p<=46));
                const float mult = isop ? 8.f : 1.f;
                const float c = s + ba[0];
                ws_cm[grow] = make_float2(c * mult, mult);
            }
        }
    }

    // ---- V^T emission (opin blocks), fragment-tiled layout ----
    // element [b][kcj][ks][q4][h][v] = opin[kcj*64 + ks*32 + q4*8 + v][h]
    // thread h gathers its 64 j-values then stores 8 x half8; chunk w of
    // vals goes to offset w*2048 (ks=w>>2, q4=w&3 -> (ks*4+q4)=w).
    // lane-stride of each store = 16B -> 1KB contiguous per wave-store.
    if (mat == 1) {
        const int h = tid;
        const size_t b = g0 >> 11;
        const int kcj = (int)((g0 & 2047) >> 6);       // this block's 64-j chunk
        const int kc = h >> 5, kq = (h >> 3) & 3, jh = h & 7;
        _Float16 vals[64];
#pragma unroll
        for (int r = 0; r < 64; ++r)
            vals[r] = a_lds[r >> 4][kc][((r & 15) + 16 * kq) * 8 + jh];
        _Float16* dst = vtg + ((size_t)b * 32 + kcj) * 16384 + h * 8;
#pragma unroll
        for (int w = 0; w < 8; ++w)
            *(half8*)(dst + w * 2048) = *(half8*)&vals[w * 8];
    }
}

// ---------------------------------------------------------------------------
// attn v4: one block = (batch b, 32-row i-tile). 256 thr, 4 waves, grid 512
//          -> 2 blocks/CU so barriers/latency of one block hide under the
//          other (v2/v3's 1 block/CU exposed every stall).
//  - scores once per (i,j); row-local softmax (8 lanes/row, 3 shfls)
//  - bias via LDS table base[d]*log2e; exp via raw v_exp_f32
//  - V^T B-fragments: pinned asm global_load_dwordx4 from the fragment-tiled
//    vtg (16B/lane contiguous, 16-lane 256B runs -> 8 lines/wave-inst;
//    v3's [h][j] layout was 64 lines/wave-inst = ~4096 TA cycles/chunk,
//    which matched the measured 7660 cyc/chunk almost exactly)
//  - alpha read as 2 x ds_read_b128 (was 8 scalar reads)
//  - ONE __syncthreads per chunk (P and alpha double-buffered in LDS)
// ---------------------------------------------------------------------------
__global__ __launch_bounds__(256, 2) void attn_kernel(
    const float* __restrict__ ws_st, const float2* __restrict__ ws_cm,
    const _Float16* __restrict__ vtg, float* __restrict__ out)
{
    __shared__ float t_lds[2048];                           // base[d]*log2e, 8 KB
    __shared__ __align__(16) _Float16 p_lds[2][2][2][512];  // [buf][rt][ks][frag-linear]
    __shared__ __align__(16) float alpha_lds[2][32];
    __shared__ float z_lds[32];

    const int tid  = threadIdx.x;
    const int lane = tid & 63;
    const int hq   = tid >> 6;                // wave id = h quarter (0..3)
    const int em   = lane & 15;
    const int q4   = lane >> 4;

    const int b  = blockIdx.x & 7;            // XCD-affine batch mapping
    const int i0 = (blockIdx.x >> 3) * 32;

    const int row = tid >> 3;                 // scoring row 0..31 (8 lanes/row)
    const int jg  = tid & 7;                  // 8-j group within chunk
    const int gi  = i0 + row;

    // ---- bias table: d==0 ? 0.5 : 1/log2(2+d), scaled by log2(e) ----
#pragma unroll
    for (int v = 0; v < 8; ++v) {
        const int d = tid * 8 + v;
        const float bv = (d == 0) ? 0.5f : 1.0f / __log2f(2.f + (float)d);
        t_lds[d] = bv * 1.44269504088896f;
    }

    const float sti = ws_st[b * 2048 + gi];
    // fragment-tiled V^T base for this lane: [b][kc][ks][q4][h=hq*64+ht*16+em][8]
    const _Float16* __restrict__ vb =
        vtg + ((size_t)b * 32) * 16384 + q4 * 2048 + (hq * 64 + em) * 8;

    f32x4 acc[2][4];
#pragma unroll
    for (int rt = 0; rt < 2; ++rt)
#pragma unroll
        for (int ht = 0; ht < 4; ++ht) acc[rt][ht] = (f32x4){0.f, 0.f, 0.f, 0.f};
    float m_run = -1e30f;
    float zacc  = 0.f;

    // pinned V^T fragment buffer: 8 x 16B = 32 VGPRs
    f32x4 vbuf[2][4];
#pragma unroll
    for (int ks = 0; ks < 2; ++ks)
#pragma unroll
        for (int ht = 0; ht < 4; ++ht)
            asm volatile("global_load_dwordx4 %0, %1, off"
                         : "=v"(vbuf[ks][ht])
                         : "v"(vb + ks * 8192 + ht * 128));

    __syncthreads();   // t_lds ready (also drains prologue loads harmlessly)

    for (int kc = 0; kc < 32; ++kc) {
        const int j0  = kc * 64;
        const int buf = kc & 1;

        // --- scores: 8 j per lane, bias from table ---
        float s_arr[8];
        float mx = -1e30f;
        {
            const float4* __restrict__ cmp =
                (const float4*)(ws_cm + b * 2048 + j0 + jg * 8);
#pragma unroll
            for (int w = 0; w < 4; ++w) {
                const float4 c4 = cmp[w];          // {c0*m0, m0, c1*m1, m1}
                const int jj = j0 + jg * 8 + w * 2;
                int d0 = gi - jj;     d0 = d0 < 0 ? -d0 : d0;
                int d1 = gi - jj - 1; d1 = d1 < 0 ? -d1 : d1;
                const float s0 = (sti * c4.y + c4.x) * t_lds[d0];
                const float s1 = (sti * c4.w + c4.z) * t_lds[d1];
                s_arr[2 * w]     = s0;
                s_arr[2 * w + 1] = s1;
                mx = fmaxf(mx, fmaxf(s0, s1));
            }
        }
        // row max across the row's 8 lanes (consecutive, 8-aligned)
        mx = fmaxf(mx, __shfl_xor(mx, 1, 64));
        mx = fmaxf(mx, __shfl_xor(mx, 2, 64));
        mx = fmaxf(mx, __shfl_xor(mx, 4, 64));

        const float m_new = fmaxf(m_run, mx);
        const float alpha = __builtin_amdgcn_exp2f(m_run - m_new); // ==1 if no update
        float zl = 0.f;
        half8 pv;
#pragma unroll
        for (int v = 0; v < 8; ++v) {
            const float p = __builtin_amdgcn_exp2f(s_arr[v] - m_new);
            zl += p;
            pv[v] = (_Float16)p;
        }
        zacc  = zacc * alpha + zl;
        m_run = m_new;

        // P frag-linear with XOR swizzle: slot = ((r&15)^(kq<<1)) + 16*kq
        {
            const int kq = jg & 3;
            const int slot = (((row & 15) ^ (kq << 1)) + 16 * kq);
            *(half8*)&p_lds[buf][row >> 4][jg >> 2][slot * 8] = pv;
        }
        if (jg == 0) alpha_lds[buf][row] = alpha;

        __syncthreads();   // the ONLY barrier per chunk

        // --- rescale acc by per-row alpha (2 x b128 broadcast reads) ---
        {
            const float4 a0 = *(const float4*)&alpha_lds[buf][q4 * 4];
            const float4 a1 = *(const float4*)&alpha_lds[buf][16 + q4 * 4];
            float ar[2][4] = {{a0.x, a0.y, a0.z, a0.w}, {a1.x, a1.y, a1.z, a1.w}};
            bool upd = false;
#pragma unroll
            for (int rt = 0; rt < 2; ++rt)
#pragma unroll
                for (int r = 0; r < 4; ++r) upd |= (ar[rt][r] != 1.f);
            if (__any(upd)) {
#pragma unroll
                for (int rt = 0; rt < 2; ++rt)
#pragma unroll
                    for (int ht = 0; ht < 4; ++ht)
#pragma unroll
                        for (int r = 0; r < 4; ++r)
                            acc[rt][ht][r] *= ar[rt][r];
            }
        }

        // --- drain the pinned loads; fence so MFMAs can't hoist above ---
        asm volatile("s_waitcnt vmcnt(0)" ::: "memory");
        __builtin_amdgcn_sched_barrier(0);

        // --- MFMA: P(32x64) @ V^T-cols, B-fragments in pinned regs ---
        {
            const int sl8 = ((em ^ (q4 << 1)) + 16 * q4) * 8;   // read-side swizzle
#pragma unroll
            for (int ks = 0; ks < 2; ++ks) {
                const half8 a0 = *(const half8*)&p_lds[buf][0][ks][sl8];
                const half8 a1 = *(const half8*)&p_lds[buf][1][ks][sl8];
#pragma unroll
                for (int ht = 0; ht < 4; ++ht) {
                    const half8 bh = __builtin_bit_cast(half8, vbuf[ks][ht]);
                    acc[0][ht] = __builtin_amdgcn_mfma_f32_16x16x32_f16(a0, bh, acc[0][ht], 0, 0, 0);
                    acc[1][ht] = __builtin_amdgcn_mfma_f32_16x16x32_f16(a1, bh, acc[1][ht], 0, 0, 0);
                }
            }
        }

        // --- issue next chunk's fragments (regs free after MFMA consumption) ---
        if (kc < 31) {
            const _Float16* __restrict__ pnext = vb + (size_t)(kc + 1) * 16384;
#pragma unroll
            for (int ks = 0; ks < 2; ++ks)
#pragma unroll
                for (int ht = 0; ht < 4; ++ht)
                    asm volatile("global_load_dwordx4 %0, %1, off"
                                 : "=v"(vbuf[ks][ht])
                                 : "v"(pnext + ks * 8192 + ht * 128));
        }
    }

    // --- Z finalize: reduce the row's 8 lanes, publish ---
    zacc += __shfl_xor(zacc, 1, 64);
    zacc += __shfl_xor(zacc, 2, 64);
    zacc += __shfl_xor(zacc, 4, 64);
    if (jg == 0) z_lds[row] = zacc;
    __syncthreads();

    // --- epilogue: normalize, store. C/D: col=lane&15, row=(lane>>4)*4+reg ---
#pragma unroll
    for (int rt = 0; rt < 2; ++rt) {
#pragma unroll
        for (int r = 0; r < 4; ++r) {
            const int orow = rt * 16 + q4 * 4 + r;
            const float rz = 1.f / z_lds[orow];
#pragma unroll
            for (int ht = 0; ht < 4; ++ht)
                out[((size_t)b * 2048 + i0 + orow) * 256 + hq * 64 + ht * 16 + em] =
                    acc[rt][ht][r] * rz;
        }
    }
}

// ---------------------------------------------------------------------------
extern "C" void kernel_launch(void* const* d_in, const int* in_sizes, int n_in,
                              void* d_out, int out_size, void* d_ws, size_t ws_size,
                              hipStream_t stream) {
    const float* opin  = (const float*)d_in[0];
    const float* text  = (const float*)d_in[1];
    const int* pos_ids = (const int*)d_in[2];
    const float* Wt    = (const float*)d_in[3];
    const float* bt    = (const float*)d_in[4];
    const float* Wo    = (const float*)d_in[5];
    const float* wa    = (const float*)d_in[6];
    const float* ba    = (const float*)d_in[7];
    float* out         = (float*)d_out;

    // workspace: st (64 KB) | cm (128 KB) | vtg fp16 (8 MB, fragment-tiled)
    float*  ws_st = (float*)d_ws;
    float2* ws_cm = (float2*)((char*)d_ws + 65536);
    _Float16* vtg = (_Float16*)((char*)d_ws + 65536 + 131072);

    prep_kernel<<<512, 256, 0, stream>>>(opin, text, pos_ids, Wt, bt, Wo, wa, ba,
                                         ws_st, ws_cm, vtg);
    attn_kernel<<<512, 256, 0, stream>>>(ws_st, ws_cm, vtg, out);
}

// Round 4
// 139.643 us; speedup vs baseline: 1.4780x; 1.0789x over previous
//
#include <hip/hip_runtime.h>

// Problem: B=8, L=2048, H=256. fp32 in/out.
#define B_ 8
#define L_ 2048
#define H_ 256

typedef _Float16 half8 __attribute__((ext_vector_type(8)));
typedef _Float16 half4_t __attribute__((ext_vector_type(4)));
typedef float f32x4 __attribute__((ext_vector_type(4)));

__device__ __forceinline__ float fast_tanh(float x) {
    const float e2 = __expf(2.f * x);
    return 1.f - 2.f * __builtin_amdgcn_rcpf(e2 + 1.f);
}

// raw barrier: LDS-visibility only (lgkm drain), vmcnt stays in flight.
// __syncthreads would emit s_waitcnt vmcnt(0) and kill the pinned prefetch.
#define PHASE_BARRIER() do {                                   \
        asm volatile("s_waitcnt lgkmcnt(0)" ::: "memory");     \
        __builtin_amdgcn_s_barrier();                          \
        __builtin_amdgcn_sched_barrier(0);                     \
    } while (0)

// ---------------------------------------------------------------------------
// prep v5: one block = 64 rows of text (mat=0) or opin (mat=1).
//  - w_lds double-buffered (2x16KB) -> ONE raw barrier per kc (was 2 syncthreads)
//  - W chunk k+1 loaded via pinned asm global_load_dwordx4 while MFMA(k) runs;
//    vmcnt(0) wait at top of next phase (hiding ~= cvt+barrier+MFMA)
//  - vtg emitted in MFMA-fragment-tiled layout [b][kc][ks][q4][h][j8]
// ---------------------------------------------------------------------------
__global__ __launch_bounds__(256, 2) void prep_kernel(
    const float* __restrict__ opin, const float* __restrict__ text,
    const int* __restrict__ pos_ids,
    const float* __restrict__ Wt, const float* __restrict__ bt,
    const float* __restrict__ Wo, const float* __restrict__ wa,
    const float* __restrict__ ba,
    float* __restrict__ ws_st, float2* __restrict__ ws_cm,
    _Float16* __restrict__ vtg)
{
    __shared__ __align__(16) _Float16 a_lds[4][8][512];     // 32 KB
    __shared__ __align__(16) _Float16 w_lds[2][16][512];    // 32 KB double-buffered

    const int tid  = threadIdx.x;
    const int lane = tid & 63;
    const int rg   = tid >> 6;                 // wave id = 16-row group
    const int mat  = blockIdx.x & 1;           // 0=text, 1=opin
    const size_t g0 = (size_t)(blockIdx.x >> 1) * 64;   // first flattened row (b*L+i)

    const float* __restrict__ src = mat ? opin : text;
    const float* __restrict__ W   = mat ? Wo   : Wt;

    f32x4 wregA[8], wregB[8];
#define ISSUE_W(DST, KC) do {                                                   \
        _Pragma("unroll")                                                       \
        for (int p = 0; p < 8; ++p) {                                           \
            const float* p_ = W + (p * 32 + (tid >> 3)) * 256 + (KC) * 32 +     \
                              (tid & 7) * 4;                                    \
            asm volatile("global_load_dwordx4 %0, %1, off"                      \
                         : "=v"(DST[p]) : "v"(p_));                             \
        }                                                                       \
    } while (0)

    ISSUE_W(wregA, 0);

    // ---- stage A: 64 rows x 256 k, fp32 -> fp16, frag-linear per (rg, kc) ----
    for (int v = 0; v < 16; ++v) {
        const int idx = v * 256 + tid;      // float4 index in 64x64 grid
        const int row = idx >> 6;           // 0..63
        const int k   = (idx & 63) * 4;     // 0..252
        const float4 f = *(const float4*)(src + (g0 + row) * 256 + k);
        half4_t h = { (_Float16)f.x, (_Float16)f.y, (_Float16)f.z, (_Float16)f.w };
        const int off = ((row & 15) + 16 * ((k >> 3) & 3)) * 8 + (k & 7); // k&7 in {0,4}
        *(half4_t*)&a_lds[row >> 4][k >> 5][off] = h;
    }
    PHASE_BARRIER();   // a_lds visible

    f32x4 acc[16];
#pragma unroll
    for (int nt = 0; nt < 16; ++nt) acc[nt] = (f32x4){0.f, 0.f, 0.f, 0.f};

    auto wbody = [&](const int kc, f32x4 (&cur)[8], f32x4 (&nxt)[8]) {
        asm volatile("s_waitcnt vmcnt(0)" ::: "memory");   // cur's 8 loads done
        __builtin_amdgcn_sched_barrier(0);
        if (kc < 7) ISSUE_W(nxt, kc + 1);
        // cvt + store cur -> w_lds[kc&1]
#pragma unroll
        for (int p = 0; p < 8; ++p) {
            const int n = p * 32 + (tid >> 3);
            const int k = (tid & 7) * 4;
            const float4 f = __builtin_bit_cast(float4, cur[p]);
            half4_t h = { (_Float16)f.x, (_Float16)f.y, (_Float16)f.z, (_Float16)f.w };
            const int off = ((n & 15) + 16 * (k >> 3)) * 8 + (k & 7);
            *(half4_t*)&w_lds[kc & 1][n >> 4][off] = h;
        }
        PHASE_BARRIER();   // w_lds[kc&1] visible; vmcnt (nxt loads) stays in flight
        const half8 afrag = *(const half8*)&a_lds[rg][kc][lane * 8];
#pragma unroll
        for (int nt = 0; nt < 16; ++nt) {
            const half8 bfrag = *(const half8*)&w_lds[kc & 1][nt][lane * 8];
            acc[nt] = __builtin_amdgcn_mfma_f32_16x16x32_f16(afrag, bfrag, acc[nt], 0, 0, 0);
        }
    };
    for (int kc = 0; kc < 8; kc += 2) {
        wbody(kc,     wregA, wregB);
        wbody(kc + 1, wregB, wregA);
    }
#undef ISSUE_W

    // ---- epilogue: rowsum_n( tanh(acc + bt?) * wa ) ----
    const int em = lane & 15, q = lane >> 4;
    float rowsum[4] = {0.f, 0.f, 0.f, 0.f};
#pragma unroll
    for (int nt = 0; nt < 16; ++nt) {
        const int col  = nt * 16 + em;
        const float btv = mat ? 0.f : bt[col];
        const float wav = wa[mat * 256 + col];
#pragma unroll
        for (int r = 0; r < 4; ++r)
            rowsum[r] += fast_tanh(acc[nt][r] + btv) * wav;
    }
#pragma unroll
    for (int r = 0; r < 4; ++r) {
        float s = rowsum[r];
        s += __shfl_xor(s, 1, 64);
        s += __shfl_xor(s, 2, 64);
        s += __shfl_xor(s, 4, 64);
        s += __shfl_xor(s, 8, 64);
        if (em == 0) {
            const size_t grow = g0 + rg * 16 + q * 4 + r;
            if (mat == 0) {
                ws_st[grow] = s;
            } else {
                const int p = pos_ids[grow];
                const bool isop = (p==19)|(p==20)|(p==21)|(p==33)|(p==34)|(p==35)|((p>=41)&(p<=46));
                const float mult = isop ? 8.f : 1.f;
                const float c = s + ba[0];
                ws_cm[grow] = make_float2(c * mult, mult);
            }
        }
    }

    // ---- V^T emission (opin blocks), fragment-tiled layout ----
    // element [b][kcj][ks][q4][h][v] = opin[kcj*64 + ks*32 + q4*8 + v][h]
    // a_lds is read-only since the first barrier -> no extra barrier needed.
    if (mat == 1) {
        const int h = tid;
        const size_t b = g0 >> 11;
        const int kcj = (int)((g0 & 2047) >> 6);       // this block's 64-j chunk
        const int kc = h >> 5, kq = (h >> 3) & 3, jh = h & 7;
        _Float16 vals[64];
#pragma unroll
        for (int r = 0; r < 64; ++r)
            vals[r] = a_lds[r >> 4][kc][((r & 15) + 16 * kq) * 8 + jh];
        _Float16* dst = vtg + ((size_t)b * 32 + kcj) * 16384 + h * 8;
#pragma unroll
        for (int w = 0; w < 8; ++w)
            *(half8*)(dst + w * 2048) = *(half8*)&vals[w * 8];
    }
}

// ---------------------------------------------------------------------------
// attn v5: one block = (batch b, 32-row i-tile). 256 thr, 4 waves, grid 512,
//          2 blocks/CU. XCD-affine: b = blockIdx&7 -> each XCD reads only its
//          1 MB vtg slice (L2-resident).
//  - ws_cm staged ONCE into LDS (16 KB): no per-chunk global score loads
//  - raw PHASE_BARRIERs (lgkm only): vmcnt survives the barrier
//  - V^T fragments: 2-deep pinned pipeline, s_waitcnt vmcnt(8) -> chunk k+1's
//    8 loads stay in flight across the whole chunk (true T3/T4)
//  - phase = {issue loads k+1 | rescale | MFMA(k) || scores(k+1)} -> MFMA and
//    score VALU interleave within one region, one barrier per chunk
// ---------------------------------------------------------------------------
__global__ __launch_bounds__(256, 2) void attn_kernel(
    const float* __restrict__ ws_st, const float2* __restrict__ ws_cm,
    const _Float16* __restrict__ vtg, float* __restrict__ out)
{
    __shared__ float t_lds[2048];                           // base[d]*log2e, 8 KB
    __shared__ float cm_lds[4096];                          // {c*m, m}[j], 16 KB
    __shared__ __align__(16) _Float16 p_lds[2][2][2][512];  // [buf][rt][ks][frag-linear]
    __shared__ __align__(16) float alpha_lds[2][32];
    __shared__ float z_lds[32];

    const int tid  = threadIdx.x;
    const int lane = tid & 63;
    const int hq   = tid >> 6;                // wave id = h quarter (0..3)
    const int em   = lane & 15;
    const int q4   = lane >> 4;

    const int b  = blockIdx.x & 7;            // XCD-affine batch mapping
    const int i0 = (blockIdx.x >> 3) * 32;

    const int row = tid >> 3;                 // scoring row 0..31 (8 lanes/row)
    const int jg  = tid & 7;                  // 8-j group within chunk
    const int gi  = i0 + row;

    // fragment-tiled V^T base for this lane: [b][kc][ks][q4][h=hq*64+ht*16+em][8]
    const _Float16* __restrict__ vb =
        vtg + ((size_t)b * 32) * 16384 + q4 * 2048 + (hq * 64 + em) * 8;

    f32x4 vbA[2][4], vbB[2][4];
#define ISSUE_VB(DST, KC) do {                                                  \
        const _Float16* p_ = vb + (size_t)((KC) & 31) * 16384;                  \
        _Pragma("unroll")                                                       \
        for (int ks = 0; ks < 2; ++ks)                                          \
        _Pragma("unroll")                                                       \
        for (int ht = 0; ht < 4; ++ht)                                          \
            asm volatile("global_load_dwordx4 %0, %1, off"                      \
                         : "=v"(DST[ks][ht]) : "v"(p_ + ks * 8192 + ht * 128)); \
    } while (0)

    ISSUE_VB(vbA, 0);

    // ---- bias table: d==0 ? 0.5 : 1/log2(2+d), scaled by log2(e) ----
#pragma unroll
    for (int v = 0; v < 8; ++v) {
        const int d = tid * 8 + v;
        const float bv = (d == 0) ? 0.5f : 1.0f / __log2f(2.f + (float)d);
        t_lds[d] = bv * 1.44269504088896f;
    }
    // ---- stage ws_cm[b] (2048 float2) into LDS ----
#pragma unroll
    for (int v = 0; v < 4; ++v) {
        const int idx = (v * 256 + tid) * 4;
        *(float4*)&cm_lds[idx] =
            *(const float4*)((const float*)(ws_cm + b * 2048) + idx);
    }

    const float sti = ws_st[b * 2048 + gi];

    f32x4 acc[2][4];
#pragma unroll
    for (int rt = 0; rt < 2; ++rt)
#pragma unroll
        for (int ht = 0; ht < 4; ++ht) acc[rt][ht] = (f32x4){0.f, 0.f, 0.f, 0.f};
    float m_run = -1e30f;
    float zacc  = 0.f;

    PHASE_BARRIER();   // t_lds / cm_lds visible

    // --- scores(kc) -> P[nbuf], alpha[nbuf]; updates m_run/zacc ---
    auto scores = [&](const int kc, const int nbuf) {
        const int j0 = kc * 64;
        float s_arr[8];
        float mx = -1e30f;
        const float* __restrict__ cmp = &cm_lds[(j0 + jg * 8) * 2];
#pragma unroll
        for (int w = 0; w < 4; ++w) {
            const float4 c4 = *(const float4*)(cmp + w * 4);   // {c0*m0,m0,c1*m1,m1}
            const int jj = j0 + jg * 8 + w * 2;
            int d0 = gi - jj;     d0 = d0 < 0 ? -d0 : d0;
            int d1 = gi - jj - 1; d1 = d1 < 0 ? -d1 : d1;
            const float s0 = (sti * c4.y + c4.x) * t_lds[d0];
            const float s1 = (sti * c4.w + c4.z) * t_lds[d1];
            s_arr[2 * w]     = s0;
            s_arr[2 * w + 1] = s1;
            mx = fmaxf(mx, fmaxf(s0, s1));
        }
        mx = fmaxf(mx, __shfl_xor(mx, 1, 64));
        mx = fmaxf(mx, __shfl_xor(mx, 2, 64));
        mx = fmaxf(mx, __shfl_xor(mx, 4, 64));

        const float m_new = fmaxf(m_run, mx);
        const float alpha = __builtin_amdgcn_exp2f(m_run - m_new);
        float zl = 0.f;
        half8 pv;
#pragma unroll
        for (int v = 0; v < 8; ++v) {
            const float p = __builtin_amdgcn_exp2f(s_arr[v] - m_new);
            zl += p;
            pv[v] = (_Float16)p;
        }
        zacc  = zacc * alpha + zl;
        m_run = m_new;

        const int kq = jg & 3;
        const int slot = (((row & 15) ^ (kq << 1)) + 16 * kq);  // XOR write swizzle
        *(half8*)&p_lds[nbuf][row >> 4][jg >> 2][slot * 8] = pv;
        if (jg == 0) alpha_lds[nbuf][row] = alpha;
    };

    auto rescale = [&](const int cbuf) {
        const float4 a0 = *(const float4*)&alpha_lds[cbuf][q4 * 4];
        const float4 a1 = *(const float4*)&alpha_lds[cbuf][16 + q4 * 4];
        const float ar[2][4] = {{a0.x, a0.y, a0.z, a0.w}, {a1.x, a1.y, a1.z, a1.w}};
        bool upd = false;
#pragma unroll
        for (int rt = 0; rt < 2; ++rt)
#pragma unroll
            for (int r = 0; r < 4; ++r) upd |= (ar[rt][r] != 1.f);
        if (__any(upd)) {
#pragma unroll
            for (int rt = 0; rt < 2; ++rt)
#pragma unroll
                for (int ht = 0; ht < 4; ++ht)
#pragma unroll
                    for (int r = 0; r < 4; ++r)
                        acc[rt][ht][r] *= ar[rt][r];
        }
    };

    auto mfma_step = [&](const int cbuf, f32x4 (&vbuf)[2][4]) {
        const int sl8 = ((em ^ (q4 << 1)) + 16 * q4) * 8;   // read-side swizzle
#pragma unroll
        for (int ks = 0; ks < 2; ++ks) {
            const half8 a0 = *(const half8*)&p_lds[cbuf][0][ks][sl8];
            const half8 a1 = *(const half8*)&p_lds[cbuf][1][ks][sl8];
#pragma unroll
            for (int ht = 0; ht < 4; ++ht) {
                const half8 bh = __builtin_bit_cast(half8, vbuf[ks][ht]);
                acc[0][ht] = __builtin_amdgcn_mfma_f32_16x16x32_f16(a0, bh, acc[0][ht], 0, 0, 0);
                acc[1][ht] = __builtin_amdgcn_mfma_f32_16x16x32_f16(a1, bh, acc[1][ht], 0, 0, 0);
            }
        }
    };

    scores(0, 0);
    PHASE_BARRIER();   // P[0]/alpha[0] visible; vbA(0) still in flight

    for (int kc = 0; kc < 32; kc += 2) {
        // ---- even phase: consume buf0/vbA, produce buf1/vbB ----
        ISSUE_VB(vbB, kc + 1);
        rescale(0);
        asm volatile("s_waitcnt vmcnt(8)" ::: "memory");    // vbA arrived
        __builtin_amdgcn_sched_barrier(0);
        mfma_step(0, vbA);
        scores(kc + 1, 1);           // interleaves with MFMA (indep pipes)
        PHASE_BARRIER();

        // ---- odd phase: consume buf1/vbB, produce buf0/vbA ----
        ISSUE_VB(vbA, kc + 2);       // (kc+2)&31 wraps harmlessly at kc=30
        rescale(1);
        asm volatile("s_waitcnt vmcnt(8)" ::: "memory");    // vbB arrived
        __builtin_amdgcn_sched_barrier(0);
        mfma_step(1, vbB);
        if (kc + 2 < 32) scores(kc + 2, 0);
        PHASE_BARRIER();
    }
#undef ISSUE_VB

    // --- Z finalize: reduce the row's 8 lanes, publish ---
    zacc += __shfl_xor(zacc, 1, 64);
    zacc += __shfl_xor(zacc, 2, 64);
    zacc += __shfl_xor(zacc, 4, 64);
    if (jg == 0) z_lds[row] = zacc;
    __syncthreads();   // safe to drain here (loop done)

    // --- epilogue: normalize, store. C/D: col=lane&15, row=(lane>>4)*4+reg ---
#pragma unroll
    for (int rt = 0; rt < 2; ++rt) {
#pragma unroll
        for (int r = 0; r < 4; ++r) {
            const int orow = rt * 16 + q4 * 4 + r;
            const float rz = 1.f / z_lds[orow];
#pragma unroll
            for (int ht = 0; ht < 4; ++ht)
                out[((size_t)b * 2048 + i0 + orow) * 256 + hq * 64 + ht * 16 + em] =
                    acc[rt][ht][r] * rz;
        }
    }
}

// ---------------------------------------------------------------------------
extern "C" void kernel_launch(void* const* d_in, const int* in_sizes, int n_in,
                              void* d_out, int out_size, void* d_ws, size_t ws_size,
                              hipStream_t stream) {
    const float* opin  = (const float*)d_in[0];
    const float* text  = (const float*)d_in[1];
    const int* pos_ids = (const int*)d_in[2];
    const float* Wt    = (const float*)d_in[3];
    const float* bt    = (const float*)d_in[4];
    const float* Wo    = (const float*)d_in[5];
    const float* wa    = (const float*)d_in[6];
    const float* ba    = (const float*)d_in[7];
    float* out         = (float*)d_out;

    // workspace: st (64 KB) | cm (128 KB) | vtg fp16 (8 MB, fragment-tiled)
    float*  ws_st = (float*)d_ws;
    float2* ws_cm = (float2*)((char*)d_ws + 65536);
    _Float16* vtg = (_Float16*)((char*)d_ws + 65536 + 131072);

    prep_kernel<<<512, 256, 0, stream>>>(opin, text, pos_ids, Wt, bt, Wo, wa, ba,
                                         ws_st, ws_cm, vtg);
    attn_kernel<<<512, 256, 0, stream>>>(ws_st, ws_cm, vtg, out);
}

// Round 5
// 138.938 us; speedup vs baseline: 1.4855x; 1.0051x over previous
//
#include <hip/hip_runtime.h>

// Problem: B=8, L=2048, H=256. fp32 in/out.
#define B_ 8
#define L_ 2048
#define H_ 256

typedef _Float16 half8 __attribute__((ext_vector_type(8)));
typedef _Float16 half4_t __attribute__((ext_vector_type(4)));
typedef float f32x4 __attribute__((ext_vector_type(4)));

__device__ __forceinline__ float fast_tanh(float x) {
    const float e2 = __expf(2.f * x);
    return 1.f - 2.f * __builtin_amdgcn_rcpf(e2 + 1.f);
}

// raw barrier: LDS-visibility only (lgkm drain), vmcnt stays in flight.
// __syncthreads would emit s_waitcnt vmcnt(0) and kill the pinned prefetch.
#define PHASE_BARRIER() do {                                   \
        asm volatile("s_waitcnt lgkmcnt(0)" ::: "memory");     \
        __builtin_amdgcn_s_barrier();                          \
        __builtin_amdgcn_sched_barrier(0);                     \
    } while (0)

// ---------------------------------------------------------------------------
// prep (unchanged from R4): one block = 64 rows of text (mat=0) or opin (mat=1).
//  - w_lds double-buffered, pinned W prefetch, raw barriers
//  - vtg emitted in MFMA-fragment-tiled layout [b][kc][ks][q4][h][j8]
// ---------------------------------------------------------------------------
__global__ __launch_bounds__(256, 2) void prep_kernel(
    const float* __restrict__ opin, const float* __restrict__ text,
    const int* __restrict__ pos_ids,
    const float* __restrict__ Wt, const float* __restrict__ bt,
    const float* __restrict__ Wo, const float* __restrict__ wa,
    const float* __restrict__ ba,
    float* __restrict__ ws_st, float2* __restrict__ ws_cm,
    _Float16* __restrict__ vtg)
{
    __shared__ __align__(16) _Float16 a_lds[4][8][512];     // 32 KB
    __shared__ __align__(16) _Float16 w_lds[2][16][512];    // 32 KB double-buffered

    const int tid  = threadIdx.x;
    const int lane = tid & 63;
    const int rg   = tid >> 6;                 // wave id = 16-row group
    const int mat  = blockIdx.x & 1;           // 0=text, 1=opin
    const size_t g0 = (size_t)(blockIdx.x >> 1) * 64;   // first flattened row (b*L+i)

    const float* __restrict__ src = mat ? opin : text;
    const float* __restrict__ W   = mat ? Wo   : Wt;

    f32x4 wregA[8], wregB[8];
#define ISSUE_W(DST, KC) do {                                                   \
        _Pragma("unroll")                                                       \
        for (int p = 0; p < 8; ++p) {                                           \
            const float* p_ = W + (p * 32 + (tid >> 3)) * 256 + (KC) * 32 +     \
                              (tid & 7) * 4;                                    \
            asm volatile("global_load_dwordx4 %0, %1, off"                      \
                         : "=v"(DST[p]) : "v"(p_));                             \
        }                                                                       \
    } while (0)

    ISSUE_W(wregA, 0);

    // ---- stage A: 64 rows x 256 k, fp32 -> fp16, frag-linear per (rg, kc) ----
    for (int v = 0; v < 16; ++v) {
        const int idx = v * 256 + tid;      // float4 index in 64x64 grid
        const int row = idx >> 6;           // 0..63
        const int k   = (idx & 63) * 4;     // 0..252
        const float4 f = *(const float4*)(src + (g0 + row) * 256 + k);
        half4_t h = { (_Float16)f.x, (_Float16)f.y, (_Float16)f.z, (_Float16)f.w };
        const int off = ((row & 15) + 16 * ((k >> 3) & 3)) * 8 + (k & 7); // k&7 in {0,4}
        *(half4_t*)&a_lds[row >> 4][k >> 5][off] = h;
    }
    PHASE_BARRIER();   // a_lds visible

    f32x4 acc[16];
#pragma unroll
    for (int nt = 0; nt < 16; ++nt) acc[nt] = (f32x4){0.f, 0.f, 0.f, 0.f};

    auto wbody = [&](const int kc, f32x4 (&cur)[8], f32x4 (&nxt)[8]) {
        asm volatile("s_waitcnt vmcnt(0)" ::: "memory");   // cur's 8 loads done
        __builtin_amdgcn_sched_barrier(0);
        if (kc < 7) ISSUE_W(nxt, kc + 1);
        // cvt + store cur -> w_lds[kc&1]
#pragma unroll
        for (int p = 0; p < 8; ++p) {
            const int n = p * 32 + (tid >> 3);
            const int k = (tid & 7) * 4;
            const float4 f = __builtin_bit_cast(float4, cur[p]);
            half4_t h = { (_Float16)f.x, (_Float16)f.y, (_Float16)f.z, (_Float16)f.w };
            const int off = ((n & 15) + 16 * (k >> 3)) * 8 + (k & 7);
            *(half4_t*)&w_lds[kc & 1][n >> 4][off] = h;
        }
        PHASE_BARRIER();   // w_lds[kc&1] visible; vmcnt (nxt loads) stays in flight
        const half8 afrag = *(const half8*)&a_lds[rg][kc][lane * 8];
#pragma unroll
        for (int nt = 0; nt < 16; ++nt) {
            const half8 bfrag = *(const half8*)&w_lds[kc & 1][nt][lane * 8];
            acc[nt] = __builtin_amdgcn_mfma_f32_16x16x32_f16(afrag, bfrag, acc[nt], 0, 0, 0);
        }
    };
    for (int kc = 0; kc < 8; kc += 2) {
        wbody(kc,     wregA, wregB);
        wbody(kc + 1, wregB, wregA);
    }
#undef ISSUE_W

    // ---- epilogue: rowsum_n( tanh(acc + bt?) * wa ) ----
    const int em = lane & 15, q = lane >> 4;
    float rowsum[4] = {0.f, 0.f, 0.f, 0.f};
#pragma unroll
    for (int nt = 0; nt < 16; ++nt) {
        const int col  = nt * 16 + em;
        const float btv = mat ? 0.f : bt[col];
        const float wav = wa[mat * 256 + col];
#pragma unroll
        for (int r = 0; r < 4; ++r)
            rowsum[r] += fast_tanh(acc[nt][r] + btv) * wav;
    }
#pragma unroll
    for (int r = 0; r < 4; ++r) {
        float s = rowsum[r];
        s += __shfl_xor(s, 1, 64);
        s += __shfl_xor(s, 2, 64);
        s += __shfl_xor(s, 4, 64);
        s += __shfl_xor(s, 8, 64);
        if (em == 0) {
            const size_t grow = g0 + rg * 16 + q * 4 + r;
            if (mat == 0) {
                ws_st[grow] = s;
            } else {
                const int p = pos_ids[grow];
                const bool isop = (p==19)|(p==20)|(p==21)|(p==33)|(p==34)|(p==35)|((p>=41)&(p<=46));
                const float mult = isop ? 8.f : 1.f;
                const float c = s + ba[0];
                ws_cm[grow] = make_float2(c * mult, mult);
            }
        }
    }

    // ---- V^T emission (opin blocks), fragment-tiled layout ----
    if (mat == 1) {
        const int h = tid;
        const size_t b = g0 >> 11;
        const int kcj = (int)((g0 & 2047) >> 6);       // this block's 64-j chunk
        const int kc = h >> 5, kq = (h >> 3) & 3, jh = h & 7;
        _Float16 vals[64];
#pragma unroll
        for (int r = 0; r < 64; ++r)
            vals[r] = a_lds[r >> 4][kc][((r & 15) + 16 * kq) * 8 + jh];
        _Float16* dst = vtg + ((size_t)b * 32 + kcj) * 16384 + h * 8;
#pragma unroll
        for (int w = 0; w < 8; ++w)
            *(half8*)(dst + w * 2048) = *(half8*)&vals[w * 8];
    }
}

// ---------------------------------------------------------------------------
// attn v6: one block = (batch b, 32-row i-tile). 512 thr / 8 waves, grid 512
//          -> 16 waves/CU = 4 waves/SIMD (was 2: Occupancy=16% showed grid
//          was the limiter; all pipes <35% busy = latency-bound).
//  - wave (kh, hq): kh = j-half of each chunk, hq = h-quarter. Each wave
//    accumulates a PARTIAL PV over its 32 j -> V frags read ONCE per block
//    (L2 traffic unchanged); one-time LDS cross-reduce in epilogue.
//  - scores: 512 thr, 4 j/thread, 16 lanes/row (4 shfl_xor row-max)
//  - raw PHASE_BARRIER (lgkm only), 2-deep pinned V prefetch, vmcnt(4)
// ---------------------------------------------------------------------------
__global__ __launch_bounds__(512, 4) void attn_kernel(
    const float* __restrict__ ws_st, const float2* __restrict__ ws_cm,
    const _Float16* __restrict__ vtg, float* __restrict__ out)
{
    __shared__ float t_lds[2048];                           // base[d]*log2e, 8 KB
    __shared__ float cm_lds[4096];                          // {c*m, m}[j], 16 KB
    __shared__ __align__(16) _Float16 p_lds[2][2][2][512];  // [buf][rt][ks][frag-linear] 8 KB
    __shared__ __align__(16) float alpha_lds[2][32];
    __shared__ float z_lds[32];
    __shared__ float red_lds[32][260];                      // padded: conflict-free reduce

    const int tid  = threadIdx.x;
    const int lane = tid & 63;
    const int wid  = tid >> 6;                // 0..7
    const int hq   = wid & 3;                 // h quarter
    const int kh   = wid >> 2;                // j half of each chunk (K-split)
    const int em   = lane & 15;
    const int q4   = lane >> 4;

    const int b  = blockIdx.x & 7;            // XCD-affine batch mapping
    const int i0 = (blockIdx.x >> 3) * 32;

    const int row = tid >> 4;                 // scoring row 0..31 (16 lanes/row)
    const int jg  = tid & 15;                 // 4-j group within chunk
    const int gi  = i0 + row;

    // fragment-tiled V^T base: [b][kc][ks=kh][q4][h=hq*64+ht*16+em][8]
    const _Float16* __restrict__ vb =
        vtg + (size_t)b * 524288 + kh * 8192 + q4 * 2048 + (hq * 64 + em) * 8;

    f32x4 vbA[4], vbB[4];
#define ISSUE_VB(DST, KC) do {                                                  \
        const _Float16* p_ = vb + (size_t)((KC) & 31) * 16384;                  \
        _Pragma("unroll")                                                       \
        for (int ht = 0; ht < 4; ++ht)                                          \
            asm volatile("global_load_dwordx4 %0, %1, off"                      \
                         : "=v"(DST[ht]) : "v"(p_ + ht * 128));                 \
    } while (0)

    ISSUE_VB(vbA, 0);

    // ---- bias table: d==0 ? 0.5 : 1/log2(2+d), scaled by log2(e) ----
#pragma unroll
    for (int v = 0; v < 4; ++v) {
        const int d = tid * 4 + v;
        const float bv = (d == 0) ? 0.5f : 1.0f / __log2f(2.f + (float)d);
        t_lds[d] = bv * 1.44269504088896f;
    }
    // ---- stage ws_cm[b] (2048 float2 = 4096 f32) into LDS ----
#pragma unroll
    for (int v = 0; v < 2; ++v) {
        const int idx = (v * 512 + tid) * 4;
        *(float4*)&cm_lds[idx] =
            *(const float4*)((const float*)(ws_cm + b * 2048) + idx);
    }

    const float sti = ws_st[b * 2048 + gi];

    f32x4 acc[2][4];   // partial PV over this wave's j-half
#pragma unroll
    for (int rt = 0; rt < 2; ++rt)
#pragma unroll
        for (int ht = 0; ht < 4; ++ht) acc[rt][ht] = (f32x4){0.f, 0.f, 0.f, 0.f};
    float m_run = -1e30f;
    float zacc  = 0.f;

    PHASE_BARRIER();   // t_lds / cm_lds visible

    // --- scores(kc) -> P[nbuf], alpha[nbuf]; updates m_run/zacc ---
    // thread (row, jg) handles j = j0 + jg*4 + {0..3}
    auto scores = [&](const int kc, const int nbuf) {
        const int j0 = kc * 64;
        float s_arr[4];
        float mx = -1e30f;
        const float* __restrict__ cmp = &cm_lds[(j0 + jg * 4) * 2];
        const float4 ca = *(const float4*)(cmp + 0);   // {c0*m0,m0,c1*m1,m1}
        const float4 cb = *(const float4*)(cmp + 4);   // {c2*m2,m2,c3*m3,m3}
        {
            const int jj = j0 + jg * 4;
            int d0 = gi - jj;     d0 = d0 < 0 ? -d0 : d0;
            int d1 = gi - jj - 1; d1 = d1 < 0 ? -d1 : d1;
            int d2 = gi - jj - 2; d2 = d2 < 0 ? -d2 : d2;
            int d3 = gi - jj - 3; d3 = d3 < 0 ? -d3 : d3;
            s_arr[0] = (sti * ca.y + ca.x) * t_lds[d0];
            s_arr[1] = (sti * ca.w + ca.z) * t_lds[d1];
            s_arr[2] = (sti * cb.y + cb.x) * t_lds[d2];
            s_arr[3] = (sti * cb.w + cb.z) * t_lds[d3];
            mx = fmaxf(fmaxf(s_arr[0], s_arr[1]), fmaxf(s_arr[2], s_arr[3]));
        }
        // row max across the row's 16 lanes (consecutive, 16-aligned)
        mx = fmaxf(mx, __shfl_xor(mx, 1, 64));
        mx = fmaxf(mx, __shfl_xor(mx, 2, 64));
        mx = fmaxf(mx, __shfl_xor(mx, 4, 64));
        mx = fmaxf(mx, __shfl_xor(mx, 8, 64));

        const float m_new = fmaxf(m_run, mx);
        const float alpha = __builtin_amdgcn_exp2f(m_run - m_new);
        float zl = 0.f;
        half4_t pv;
#pragma unroll
        for (int v = 0; v < 4; ++v) {
            const float p = __builtin_amdgcn_exp2f(s_arr[v] - m_new);
            zl += p;
            pv[v] = (_Float16)p;
        }
        zacc  = zacc * alpha + zl;
        m_run = m_new;

        // P frag-linear: k = jg*4+v; ks=jg>>3; kq=(jg&7)>>1; k8=(jg&1)*4+v
        // slot XOR-swizzled to spread banks: slot = ((mrow^(kq<<1)) + 16*kq)
        {
            const int mrow = row & 15;
            const int ks = jg >> 3;
            const int kq = (jg & 7) >> 1;
            const int slot = ((mrow ^ (kq << 1)) + 16 * kq);
            *(half4_t*)&p_lds[nbuf][row >> 4][ks][slot * 8 + (jg & 1) * 4] = pv;
        }
        if (jg == 0) alpha_lds[nbuf][row] = alpha;
    };

    auto rescale = [&](const int cbuf) {
        const float4 a0 = *(const float4*)&alpha_lds[cbuf][q4 * 4];
        const float4 a1 = *(const float4*)&alpha_lds[cbuf][16 + q4 * 4];
        const float ar[2][4] = {{a0.x, a0.y, a0.z, a0.w}, {a1.x, a1.y, a1.z, a1.w}};
        bool upd = false;
#pragma unroll
        for (int rt = 0; rt < 2; ++rt)
#pragma unroll
            for (int r = 0; r < 4; ++r) upd |= (ar[rt][r] != 1.f);
        if (__any(upd)) {
#pragma unroll
            for (int rt = 0; rt < 2; ++rt)
#pragma unroll
                for (int ht = 0; ht < 4; ++ht)
#pragma unroll
                    for (int r = 0; r < 4; ++r)
                        acc[rt][ht][r] *= ar[rt][r];
        }
    };

    // MFMA: this wave's j-half only (K=32): A = P[32 rows x 32 j(kh)]
    auto mfma_step = [&](const int cbuf, f32x4 (&vbuf)[4]) {
        const int sl8 = ((em ^ (q4 << 1)) + 16 * q4) * 8;   // read-side swizzle
        const half8 a0 = *(const half8*)&p_lds[cbuf][0][kh][sl8];
        const half8 a1 = *(const half8*)&p_lds[cbuf][1][kh][sl8];
#pragma unroll
        for (int ht = 0; ht < 4; ++ht) {
            const half8 bh = __builtin_bit_cast(half8, vbuf[ht]);
            acc[0][ht] = __builtin_amdgcn_mfma_f32_16x16x32_f16(a0, bh, acc[0][ht], 0, 0, 0);
            acc[1][ht] = __builtin_amdgcn_mfma_f32_16x16x32_f16(a1, bh, acc[1][ht], 0, 0, 0);
        }
    };

    scores(0, 0);
    PHASE_BARRIER();   // P[0]/alpha[0] visible; vbA(0) still in flight

    for (int kc = 0; kc < 32; kc += 2) {
        // ---- even phase: consume buf0/vbA, produce buf1/vbB ----
        ISSUE_VB(vbB, kc + 1);
        rescale(0);
        asm volatile("s_waitcnt vmcnt(4)" ::: "memory");    // vbA arrived
        __builtin_amdgcn_sched_barrier(0);
        mfma_step(0, vbA);
        scores(kc + 1, 1);           // interleaves with MFMA (indep pipes)
        PHASE_BARRIER();

        // ---- odd phase: consume buf1/vbB, produce buf0/vbA ----
        ISSUE_VB(vbA, kc + 2);       // (kc+2)&31 wraps harmlessly at kc=30
        rescale(1);
        asm volatile("s_waitcnt vmcnt(4)" ::: "memory");    // vbB arrived
        __builtin_amdgcn_sched_barrier(0);
        mfma_step(1, vbB);
        if (kc + 2 < 32) scores(kc + 2, 0);
        PHASE_BARRIER();
    }
#undef ISSUE_VB

    // --- Z finalize: reduce the row's 16 lanes, publish ---
    zacc += __shfl_xor(zacc, 1, 64);
    zacc += __shfl_xor(zacc, 2, 64);
    zacc += __shfl_xor(zacc, 4, 64);
    zacc += __shfl_xor(zacc, 8, 64);
    if (jg == 0) z_lds[row] = zacc;

    // --- cross-wave PV reduce: kh=1 partials -> LDS, kh=0 adds ---
    if (kh == 1) {
#pragma unroll
        for (int rt = 0; rt < 2; ++rt)
#pragma unroll
            for (int ht = 0; ht < 4; ++ht)
#pragma unroll
                for (int r = 0; r < 4; ++r)
                    red_lds[rt * 16 + q4 * 4 + r][hq * 64 + ht * 16 + em] = acc[rt][ht][r];
    }
    __syncthreads();   // loop done: safe to drain everything

    // --- epilogue (kh=0 waves): add partial, normalize, store ---
    if (kh == 0) {
#pragma unroll
        for (int rt = 0; rt < 2; ++rt) {
#pragma unroll
            for (int r = 0; r < 4; ++r) {
                const int orow = rt * 16 + q4 * 4 + r;
                const float rz = 1.f / z_lds[orow];
#pragma unroll
                for (int ht = 0; ht < 4; ++ht) {
                    const float v = acc[rt][ht][r] + red_lds[orow][hq * 64 + ht * 16 + em];
                    out[((size_t)b * 2048 + i0 + orow) * 256 + hq * 64 + ht * 16 + em] = v * rz;
                }
            }
        }
    }
}

// ---------------------------------------------------------------------------
extern "C" void kernel_launch(void* const* d_in, const int* in_sizes, int n_in,
                              void* d_out, int out_size, void* d_ws, size_t ws_size,
                              hipStream_t stream) {
    const float* opin  = (const float*)d_in[0];
    const float* text  = (const float*)d_in[1];
    const int* pos_ids = (const int*)d_in[2];
    const float* Wt    = (const float*)d_in[3];
    const float* bt    = (const float*)d_in[4];
    const float* Wo    = (const float*)d_in[5];
    const float* wa    = (const float*)d_in[6];
    const float* ba    = (const float*)d_in[7];
    float* out         = (float*)d_out;

    // workspace: st (64 KB) | cm (128 KB) | vtg fp16 (8 MB, fragment-tiled)
    float*  ws_st = (float*)d_ws;
    float2* ws_cm = (float2*)((char*)d_ws + 65536);
    _Float16* vtg = (_Float16*)((char*)d_ws + 65536 + 131072);

    prep_kernel<<<512, 256, 0, stream>>>(opin, text, pos_ids, Wt, bt, Wo, wa, ba,
                                         ws_st, ws_cm, vtg);
    attn_kernel<<<512, 512, 0, stream>>>(ws_st, ws_cm, vtg, out);
}